// Round 21
// baseline (69.487 us; speedup 1.0000x reference)
//
#include <hip/hip_runtime.h>

// Problem sizes
#define NB  131072
#define ND1 40
#define ND2 10
#define NT0 120
#define NT1 5
#define NO0 3

#define NBW 32                  // batches per tile
#define XT  (NBW * ND1 * ND2)   // 12800 floats per tile
#define PK  40                  // Ybf row pitch (bf16 elems)

typedef __attribute__((ext_vector_type(8))) short  short8;
typedef __attribute__((ext_vector_type(4))) float  f32x4;

static __device__ __forceinline__ unsigned short f2bf(float f) {
    union { float f; unsigned u; } v; v.f = f;
    unsigned r = v.u + 0x7FFFu + ((v.u >> 16) & 1u);
    return (unsigned short)(r >> 16);
}

// Two 32-batch tiles per 256-thread block (2048 blocks), T14 async-split:
//   LOADX(A); COMPY(A); LOADX(B)  <- B's loads issued BEFORE the barrier
//   lgkmcnt(0)+s_barrier          <- raw barrier: does NOT drain vmcnt,
//                                    so B's loads stay in flight...
//   PHASE2(A) MFMA                <- ...hidden under A's matrix phase
//   COMPY(B); barrier; PHASE2(B)
// This closes the "no loads in flight during MFMA+epilogue" window that
// capped R19 at 4.1 TB/s (66% of achievable).
// __launch_bounds__(256) (no min-waves): xqB (60 VGPR) is live through
// PHASE2(A); the 112-reg (256,2) cap would spill. ~140 VGPR -> 8 waves/CU,
// the occupancy every best round actually ran at.
__global__ __launch_bounds__(256) void BL_36721970381090_kernel(
    const float* __restrict__ x,
    const float* __restrict__ W11,
    const float* __restrict__ fc2_w,
    const float* __restrict__ bias1,
    const float* __restrict__ W12,
    const float* __restrict__ fc4_w,
    const float* __restrict__ bias2,
    float* __restrict__ out)
{
    __shared__ __align__(16) unsigned short YbfA[NT1 * NBW * PK]; // 12800 B
    __shared__ __align__(16) unsigned short YbfB[NT1 * NBW * PK]; // 12800 B
    __shared__ float biasL[128 * NT1];                            //  2560 B
    __shared__ float w12L[NO0 * 128];                             //  1536 B
    __shared__ float b2L[4];
    __shared__ float redLA[4 * NO0 * NBW];                        //  1536 B
    __shared__ float redLB[4 * NO0 * NBW];                        //  1536 B

    const int tid = threadIdx.x;
    const int wg  = blockIdx.x;
    const int w   = tid >> 6;   // wave 0..3
    const int l   = tid & 63;
    const int lr  = l & 15;
    const int lg  = l >> 4;

    // ---------------- prologue: constants -> LDS --------------------------
    for (int i = tid; i < 128 * NT1; i += 256)
        biasL[i] = (i < NT0 * NT1) ? bias1[i] : 0.f;
    for (int i = tid; i < NO0 * 128; i += 256) {
        const int o = i >> 7, t = i & 127;
        w12L[i] = (t < NT0) ? W12[o * NT0 + t] : 0.f;
    }
    if (tid < NO0) b2L[tid] = bias2[tid];

    float fc4r[NT1];
#pragma unroll
    for (int u = 0; u < NT1; ++u) fc4r[u] = fc4_w[u];

    // A-fragments: W11 -> bf16, masked (t<120, d<40)
    short8 afr[2][2];
#pragma unroll
    for (int mt = 0; mt < 2; ++mt) {
        const int t  = w * 32 + mt * 16 + lr;
        const int tc = t < NT0 ? t : NT0 - 1;
#pragma unroll
        for (int kk = 0; kk < 2; ++kk) {
            const int cb = kk * 32 + lg * 8;
            const int cc = cb <= 32 ? cb : 0;
            const float4* pw = (const float4*)(W11 + tc * ND1 + cc);
            const float4 w0 = pw[0], w1 = pw[1];
            const bool v = (t < NT0) && (cb <= 32);
            short8 f;
            f[0] = v ? (short)f2bf(w0.x) : (short)0;
            f[1] = v ? (short)f2bf(w0.y) : (short)0;
            f[2] = v ? (short)f2bf(w0.z) : (short)0;
            f[3] = v ? (short)f2bf(w0.w) : (short)0;
            f[4] = v ? (short)f2bf(w1.x) : (short)0;
            f[5] = v ? (short)f2bf(w1.y) : (short)0;
            f[6] = v ? (short)f2bf(w1.z) : (short)0;
            f[7] = v ? (short)f2bf(w1.w) : (short)0;
            afr[mt][kk] = f;
        }
    }

    const float* gxA = x + (size_t)(2 * wg) * XT;
    const float* gxB = gxA + XT;

    // ---- lambdas ---------------------------------------------------------
    auto LOADX = [&](const float* gx, float4 (&xq)[3][5]) {
#pragma unroll
        for (int rep = 0; rep < 3; ++rep) {
            if (rep < 2 || tid < 128) {
                const int q = rep * 256 + tid;
                const float4* xr = (const float4*)(gx + q * 20);
#pragma unroll
                for (int i = 0; i < 5; ++i) xq[rep][i] = xr[i];
            }
        }
    };
    auto COMPY = [&](const float4 (&xq)[3][5], unsigned short* Yb) {
        unsigned* Yw = (unsigned*)Yb;
#pragma unroll
        for (int rep = 0; rep < 3; ++rep) {
            if (rep < 2 || tid < 128) {
                const int q = rep * 256 + tid;
                const int batch = q / 20;
                const int pair  = q - batch * 20;
                const float* xv = (const float*)&xq[rep][0];
#pragma unroll
                for (int u = 0; u < NT1; ++u) {
                    float a0 = 0.f, a1 = 0.f;
#pragma unroll
                    for (int s = 0; s < ND2; ++s) {
                        const float fw = fc2_w[u * ND2 + s];   // uniform s_load
                        a0 = fmaf(xv[s], fw, a0);
                        a1 = fmaf(xv[10 + s], fw, a1);
                    }
                    Yw[u * (NBW * PK / 2) + batch * (PK / 2) + pair] =
                        (unsigned)f2bf(a0) | ((unsigned)f2bf(a1) << 16);
                }
            }
        }
    };
    auto PHASE2 = [&](const unsigned short* Yb, float (&po)[2][NO0]) {
        float st[2][2][4];
#pragma unroll
        for (int mt = 0; mt < 2; ++mt)
#pragma unroll
            for (int nt = 0; nt < 2; ++nt)
#pragma unroll
                for (int r = 0; r < 4; ++r) st[mt][nt][r] = 0.f;
        const short8 zf = {0, 0, 0, 0, 0, 0, 0, 0};
#pragma unroll
        for (int u = 0; u < NT1; ++u) {
            float bv[2][4];
#pragma unroll
            for (int mt = 0; mt < 2; ++mt)
#pragma unroll
                for (int r = 0; r < 4; ++r)
                    bv[mt][r] = biasL[(w * 32 + mt * 16 + lg * 4 + r) * NT1 + u];
            const unsigned short* Yu = &Yb[u * (NBW * PK)];
#pragma unroll
            for (int nt = 0; nt < 2; ++nt) {
                const short8 b0 = *(const short8*)&Yu[(nt * 16 + lr) * PK + lg * 8];
                short8 b1 = zf;
                if (lg == 0) b1 = *(const short8*)&Yu[(nt * 16 + lr) * PK + 32];
#pragma unroll
                for (int mt = 0; mt < 2; ++mt) {
                    f32x4 z = {0.f, 0.f, 0.f, 0.f};
                    z = __builtin_amdgcn_mfma_f32_16x16x32_bf16(afr[mt][0], b0, z, 0, 0, 0);
                    z = __builtin_amdgcn_mfma_f32_16x16x32_bf16(afr[mt][1], b1, z, 0, 0, 0);
#pragma unroll
                    for (int r = 0; r < 4; ++r)
                        st[mt][nt][r] += fc4r[u] * fmaxf(z[r] + bv[mt][r], 0.f);
                }
            }
        }
#pragma unroll
        for (int nt = 0; nt < 2; ++nt)
#pragma unroll
            for (int o = 0; o < NO0; ++o) {
                float a = 0.f;
#pragma unroll
                for (int mt = 0; mt < 2; ++mt)
#pragma unroll
                    for (int r = 0; r < 4; ++r)
                        a = fmaf(w12L[o * 128 + (w * 32 + mt * 16 + lg * 4 + r)],
                                 st[mt][nt][r], a);
                a += __shfl_xor(a, 16, 64);
                a += __shfl_xor(a, 32, 64);
                po[nt][o] = a;
            }
    };
    auto REDW = [&](float* redL, const float (&po)[2][NO0]) {
        if (l < 16) {
#pragma unroll
            for (int nt = 0; nt < 2; ++nt)
#pragma unroll
                for (int o = 0; o < NO0; ++o)
                    redL[(w * NO0 + o) * NBW + nt * 16 + l] = po[nt][o];
        }
    };
    auto OUTW = [&](const float* redL, int tileIdx) {
        if (tid < NO0 * NBW) {                 // 96 threads
            const int o  = tid >> 5;
            const int bc = tid & 31;
            const float s = redL[(0 * NO0 + o) * NBW + bc]
                          + redL[(1 * NO0 + o) * NBW + bc]
                          + redL[(2 * NO0 + o) * NBW + bc]
                          + redL[(3 * NO0 + o) * NBW + bc]
                          + b2L[o];
            out[((size_t)(2 * wg + tileIdx) * NBW + bc) * NO0 + o] = s;
        }
    };

    // ---- pipeline --------------------------------------------------------
    float4 xqA[3][5], xqB[3][5];

    LOADX(gxA, xqA);
    COMPY(xqA, YbfA);            // waits A loads, writes YbfA
    LOADX(gxB, xqB);             // B loads IN FLIGHT across the barrier

    asm volatile("s_waitcnt lgkmcnt(0)" ::: "memory");  // YbfA writes done
    __builtin_amdgcn_s_barrier();                        // no vmcnt drain

    float poA[2][NO0];
    PHASE2(YbfA, poA);           // MFMA(A) hides B's load latency
    COMPY(xqB, YbfB);            // consume B loads, write YbfB
    REDW(redLA, poA);

    asm volatile("s_waitcnt lgkmcnt(0)" ::: "memory");  // redLA + YbfB done
    __builtin_amdgcn_s_barrier();

    OUTW(redLA, 0);
    float poB[2][NO0];
    PHASE2(YbfB, poB);
    REDW(redLB, poB);

    asm volatile("s_waitcnt lgkmcnt(0)" ::: "memory");
    __builtin_amdgcn_s_barrier();

    OUTW(redLB, 1);
}

extern "C" void kernel_launch(void* const* d_in, const int* in_sizes, int n_in,
                              void* d_out, int out_size, void* d_ws, size_t ws_size,
                              hipStream_t stream) {
    const float* x      = (const float*)d_in[0];
    const float* W11    = (const float*)d_in[1];
    const float* fc2_w  = (const float*)d_in[2];
    const float* bias1  = (const float*)d_in[3];
    const float* W12    = (const float*)d_in[4];
    const float* fc4_w  = (const float*)d_in[5];
    const float* bias2  = (const float*)d_in[6];
    float* out = (float*)d_out;

    const int blocks = NB / (2 * NBW);   // 2048
    BL_36721970381090_kernel<<<blocks, 256, 0, stream>>>(
        x, W11, fc2_w, bias1, W12, fc4_w, bias2, out);
}

// Round 22
// 44.122 us; speedup vs baseline: 1.5749x; 1.5749x over previous
//
#include <hip/hip_runtime.h>

// Problem sizes
#define NB  131072
#define ND1 40
#define ND2 10
#define NT0 120
#define NT1 5
#define NO0 3

#define NBW 32                  // batches per workgroup
#define XTILE (NBW * ND1 * ND2) // 12800 floats
#define PK  40                  // Ybf row pitch (bf16 elems)

typedef __attribute__((ext_vector_type(8))) short  short8;
typedef __attribute__((ext_vector_type(4))) float  f32x4;

// R19 geometry (best: 50.7 us) + two phase-1 micro-levers:
//  (1) explicit load-all-then-compute: all 12.5 float4/thread issued before
//      any FMA -> full 200 B/thread in flight (Little's-law depth);
//  (2) v_cvt_pk_bf16_f32 for the bf16 pack: 5 ops/unit vs ~35 for the
//      integer-emulated round-to-nearest-even (same RNE semantics).
// Everything else identical to R19. (In-block pipelining: tested 3x, always
// loses to implicit cross-block overlap — R16/R21.)
__global__ __launch_bounds__(256, 2) void BL_36721970381090_kernel(
    const float* __restrict__ x,
    const float* __restrict__ W11,
    const float* __restrict__ fc2_w,
    const float* __restrict__ bias1,
    const float* __restrict__ W12,
    const float* __restrict__ fc4_w,
    const float* __restrict__ bias2,
    float* __restrict__ out)
{
    __shared__ __align__(16) unsigned short Ybf[NT1 * NBW * PK]; // 12800 B
    __shared__ float biasL[128 * NT1];                           //  2560 B
    __shared__ float w12L[NO0 * 128];                            //  1536 B
    __shared__ float b2L[4];
    __shared__ float redL[4 * NO0 * NBW];                        //  1536 B

    const int tid = threadIdx.x;
    const int wg  = blockIdx.x;
    const int w   = tid >> 6;   // wave 0..3
    const int l   = tid & 63;
    const int lr  = l & 15;     // A row / B col within 16-tile
    const int lg  = l >> 4;     // k-group

    // ---------------- prologue: constants -> LDS --------------------------
    for (int i = tid; i < 128 * NT1; i += 256)
        biasL[i] = (i < NT0 * NT1) ? bias1[i] : 0.f;
    for (int i = tid; i < NO0 * 128; i += 256) {
        const int o = i >> 7, t = i & 127;
        w12L[i] = (t < NT0) ? W12[o * NT0 + t] : 0.f;
    }
    if (tid < NO0) b2L[tid] = bias2[tid];

    float fc4r[NT1];
#pragma unroll
    for (int u = 0; u < NT1; ++u) fc4r[u] = fc4_w[u];

    // A-fragments: W11 -> bf16, masked (t<120, d<40)
    short8 afr[2][2];
#pragma unroll
    for (int mt = 0; mt < 2; ++mt) {
        const int t  = w * 32 + mt * 16 + lr;
        const int tc = t < NT0 ? t : NT0 - 1;
#pragma unroll
        for (int kk = 0; kk < 2; ++kk) {
            const int cb = kk * 32 + lg * 8;
            const int cc = cb <= 32 ? cb : 0;
            const float4* pw = (const float4*)(W11 + tc * ND1 + cc);
            const float4 w0 = pw[0], w1 = pw[1];
            const bool v = (t < NT0) && (cb <= 32);
            unsigned p01, p23, p45, p67;
            asm("v_cvt_pk_bf16_f32 %0, %1, %2" : "=v"(p01) : "v"(w0.x), "v"(w0.y));
            asm("v_cvt_pk_bf16_f32 %0, %1, %2" : "=v"(p23) : "v"(w0.z), "v"(w0.w));
            asm("v_cvt_pk_bf16_f32 %0, %1, %2" : "=v"(p45) : "v"(w1.x), "v"(w1.y));
            asm("v_cvt_pk_bf16_f32 %0, %1, %2" : "=v"(p67) : "v"(w1.z), "v"(w1.w));
            short8 f;
            f[0] = v ? (short)(p01 & 0xFFFF) : (short)0;
            f[1] = v ? (short)(p01 >> 16)    : (short)0;
            f[2] = v ? (short)(p23 & 0xFFFF) : (short)0;
            f[3] = v ? (short)(p23 >> 16)    : (short)0;
            f[4] = v ? (short)(p45 & 0xFFFF) : (short)0;
            f[5] = v ? (short)(p45 >> 16)    : (short)0;
            f[6] = v ? (short)(p67 & 0xFFFF) : (short)0;
            f[7] = v ? (short)(p67 >> 16)    : (short)0;
            afr[mt][kk] = f;
        }
    }

    // ---------------- phase 1: load-all, then compute ---------------------
    {
        const float* gx = x + (size_t)wg * XTILE;
        unsigned* Yw = (unsigned*)Ybf;
        const bool act2 = (tid < 128);

        float4 xq0[5], xq1[5], xq2[5];
        const float4* xr0 = (const float4*)(gx + (0 * 256 + tid) * 20);
        const float4* xr1 = (const float4*)(gx + (1 * 256 + tid) * 20);
        const float4* xr2 = (const float4*)(gx + (2 * 256 + tid) * 20);
#pragma unroll
        for (int i = 0; i < 5; ++i) xq0[i] = xr0[i];
#pragma unroll
        for (int i = 0; i < 5; ++i) xq1[i] = xr1[i];
        if (act2) {
#pragma unroll
            for (int i = 0; i < 5; ++i) xq2[i] = xr2[i];
        }

        const float4* bufs[3] = {xq0, xq1, xq2};
#pragma unroll
        for (int rep = 0; rep < 3; ++rep) {
            if (rep < 2 || act2) {
                const int q = rep * 256 + tid;
                const int batch = q / 20;
                const int pair  = q - batch * 20;
                const float* xv = (const float*)bufs[rep];
#pragma unroll
                for (int u = 0; u < NT1; ++u) {
                    float a0 = 0.f, a1 = 0.f;
#pragma unroll
                    for (int s = 0; s < ND2; ++s) {
                        const float fw = fc2_w[u * ND2 + s];   // uniform: s_load
                        a0 = fmaf(xv[s], fw, a0);
                        a1 = fmaf(xv[10 + s], fw, a1);
                    }
                    unsigned pk;
                    asm("v_cvt_pk_bf16_f32 %0, %1, %2" : "=v"(pk) : "v"(a0), "v"(a1));
                    Yw[u * (NBW * PK / 2) + batch * (PK / 2) + pair] = pk;
                }
            }
        }
    }
    __syncthreads();   // Ybf + constants visible

    // ---------------- phase 2: MFMA + fused relu/fc4 ----------------------
    float st[2][2][4];          // [m-tile][n-tile][reg]
#pragma unroll
    for (int mt = 0; mt < 2; ++mt)
#pragma unroll
        for (int nt = 0; nt < 2; ++nt)
#pragma unroll
            for (int r = 0; r < 4; ++r) st[mt][nt][r] = 0.f;

    const short8 zf = {0, 0, 0, 0, 0, 0, 0, 0};
#pragma unroll
    for (int u = 0; u < NT1; ++u) {
        float bv[2][4];
#pragma unroll
        for (int mt = 0; mt < 2; ++mt)
#pragma unroll
            for (int r = 0; r < 4; ++r)
                bv[mt][r] = biasL[(w * 32 + mt * 16 + lg * 4 + r) * NT1 + u];
        const unsigned short* Yu = &Ybf[u * (NBW * PK)];
#pragma unroll
        for (int nt = 0; nt < 2; ++nt) {
            const short8 b0 = *(const short8*)&Yu[(nt * 16 + lr) * PK + lg * 8];
            short8 b1 = zf;
            if (lg == 0) b1 = *(const short8*)&Yu[(nt * 16 + lr) * PK + 32];
#pragma unroll
            for (int mt = 0; mt < 2; ++mt) {
                f32x4 z = {0.f, 0.f, 0.f, 0.f};
                z = __builtin_amdgcn_mfma_f32_16x16x32_bf16(afr[mt][0], b0, z, 0, 0, 0);
                z = __builtin_amdgcn_mfma_f32_16x16x32_bf16(afr[mt][1], b1, z, 0, 0, 0);
#pragma unroll
                for (int r = 0; r < 4; ++r)
                    st[mt][nt][r] += fc4r[u] * fmaxf(z[r] + bv[mt][r], 0.f);
            }
        }
    }

    // ---------------- epilogue: out[o,b] = sum_t W12[o,t]*st --------------
    float po[2][NO0];
#pragma unroll
    for (int nt = 0; nt < 2; ++nt)
#pragma unroll
        for (int o = 0; o < NO0; ++o) {
            float a = 0.f;
#pragma unroll
            for (int mt = 0; mt < 2; ++mt)
#pragma unroll
                for (int r = 0; r < 4; ++r)
                    a = fmaf(w12L[o * 128 + (w * 32 + mt * 16 + lg * 4 + r)],
                             st[mt][nt][r], a);
            a += __shfl_xor(a, 16, 64);
            a += __shfl_xor(a, 32, 64);
            po[nt][o] = a;
        }
    if (l < 16) {
#pragma unroll
        for (int nt = 0; nt < 2; ++nt)
#pragma unroll
            for (int o = 0; o < NO0; ++o)
                redL[(w * NO0 + o) * NBW + nt * 16 + l] = po[nt][o];
    }
    __syncthreads();

    if (tid < NO0 * NBW) {                    // 96 threads
        const int o  = tid >> 5;
        const int bc = tid & 31;
        const float s = redL[(0 * NO0 + o) * NBW + bc]
                      + redL[(1 * NO0 + o) * NBW + bc]
                      + redL[(2 * NO0 + o) * NBW + bc]
                      + redL[(3 * NO0 + o) * NBW + bc]
                      + b2L[o];
        out[((size_t)wg * NBW + bc) * NO0 + o] = s;
    }
}

extern "C" void kernel_launch(void* const* d_in, const int* in_sizes, int n_in,
                              void* d_out, int out_size, void* d_ws, size_t ws_size,
                              hipStream_t stream) {
    const float* x      = (const float*)d_in[0];
    const float* W11    = (const float*)d_in[1];
    const float* fc2_w  = (const float*)d_in[2];
    const float* bias1  = (const float*)d_in[3];
    const float* W12    = (const float*)d_in[4];
    const float* fc4_w  = (const float*)d_in[5];
    const float* bias2  = (const float*)d_in[6];
    float* out = (float*)d_out;

    const int blocks = NB / NBW;   // 4096
    BL_36721970381090_kernel<<<blocks, 256, 0, stream>>>(
        x, W11, fc2_w, bias1, W12, fc4_w, bias2, out);
}